// Round 6
// baseline (221.297 us; speedup 1.0000x reference)
//
#include <hip/hip_runtime.h>
#include <stdint.h>

typedef __attribute__((ext_vector_type(4))) int i32x4;

__device__ inline float wave_max(float v){ for(int o=32;o;o>>=1) v=fmaxf(v,__shfl_xor(v,o)); return v; }
__device__ inline float wave_min(float v){ for(int o=32;o;o>>=1) v=fminf(v,__shfl_xor(v,o)); return v; }
__device__ inline int   wave_sum(int v){ for(int o=32;o;o>>=1) v+=__shfl_xor(v,o); return v; }

// ============ fused x-max + x-quant with resident-grid spin sync ============
// grid = T/8 blocks (1024 @ T=8192) of 256 thr, <=128 VGPR, tiny LDS ->
// 4 blocks/CU co-resident by capacity => spin cannot deadlock.
__global__ __launch_bounds__(256, 4) void k_fused_quant(
    const float* __restrict__ x, const int* __restrict__ wbit,
    float* __restrict__ partials, uint32_t* __restrict__ cnt,
    uint32_t* __restrict__ xmax_bits,
    char* __restrict__ qx, int* __restrict__ Sa, int din, int nblocks){
  const int tid = threadIdx.x;
  const int r8 = tid >> 5, c32 = tid & 31;
  const long long row = (long long)blockIdx.x*8 + r8;
  const float4* xr = (const float4*)(x + row*din);
  float4 v[16];
  #pragma unroll
  for(int j=0;j<16;j++) v[j] = xr[c32 + j*32];
  float m = 0.f;
  #pragma unroll
  for(int j=0;j<16;j++) m = fmaxf(m, fmaxf(fmaxf(v[j].x,v[j].y),fmaxf(v[j].z,v[j].w)));
  m = wave_max(m);
  __shared__ float sm[4];
  if((tid&63)==0) sm[tid>>6] = m;
  __syncthreads();
  if(tid==0){
    float bm = fmaxf(fmaxf(sm[0],sm[1]),fmaxf(sm[2],sm[3]));
    partials[blockIdx.x] = bm;
    __threadfence();
    __hip_atomic_fetch_add(cnt, 1u, __ATOMIC_RELEASE, __HIP_MEMORY_SCOPE_AGENT);
    while(__hip_atomic_load(cnt, __ATOMIC_ACQUIRE, __HIP_MEMORY_SCOPE_AGENT) < (uint32_t)nblocks)
      __builtin_amdgcn_s_sleep(8);
  }
  __syncthreads();
  float mm = 0.f;
  for(int i=tid;i<nblocks;i+=256) mm = fmaxf(mm, partials[i]);
  mm = wave_max(mm);
  if((tid&63)==0) sm[tid>>6] = mm;
  __syncthreads();
  const float xmax = fmaxf(fmaxf(sm[0],sm[1]),fmaxf(sm[2],sm[3]));
  if(tid==0 && blockIdx.x==0) *xmax_bits = __float_as_uint(xmax);
  const int n = 1 << *wbit;
  const float sx = __fdiv_rn((float)(n-1), fmaxf(xmax, 1e-8f));
  uint32_t* qrow = (uint32_t*)(qx + row*din);
  int qsum = 0;
  #pragma unroll
  for(int j=0;j<16;j++){
    int q0 = (int)rintf(__fmul_rn(sx, v[j].x));
    int q1 = (int)rintf(__fmul_rn(sx, v[j].y));
    int q2 = (int)rintf(__fmul_rn(sx, v[j].z));
    int q3 = (int)rintf(__fmul_rn(sx, v[j].w));
    qsum += q0+q1+q2+q3;
    uint32_t pk = ((uint32_t)((q0-128)&0xff)) | ((uint32_t)((q1-128)&0xff)<<8) |
                  ((uint32_t)((q2-128)&0xff)<<16) | ((uint32_t)((q3-128)&0xff)<<24);
    qrow[c32 + j*32] = pk;
  }
  for(int o=16;o;o>>=1) qsum += __shfl_xor(qsum, o);
  if(c32==0) Sa[row] = qsum;
}

// one block (256 thr) per output channel row (no xmax dependency now)
__global__ void k_wstat(const float* __restrict__ w,
                        const int* __restrict__ wbit,
                        float* __restrict__ scale_w, float* __restrict__ zp_w,
                        float* __restrict__ winv,
                        int* __restrict__ cint, char* __restrict__ qw, int din){
  int row = blockIdx.x, tid = threadIdx.x;
  int lane = tid & 63, wid = tid >> 6;
  const float4* wr4 = (const float4*)(w + (long long)row*din);
  float4 a = wr4[tid*2], b = wr4[tid*2+1];
  float v[8] = {a.x,a.y,a.z,a.w,b.x,b.y,b.z,b.w};
  float mn = v[0], mx = v[0];
  for(int j=1;j<8;j++){ mn=fminf(mn,v[j]); mx=fmaxf(mx,v[j]); }
  float wmn = wave_min(mn), wmx = wave_max(mx);
  __shared__ float smn[4], smx[4];
  __shared__ float s_sw, s_zp;
  if(lane==0){ smn[wid]=wmn; smx[wid]=wmx; }
  __syncthreads();
  if(tid==0){
    float fmn = fminf(fminf(smn[0],smn[1]),fminf(smn[2],smn[3]));
    float fmx = fmaxf(fmaxf(smx[0],smx[1]),fmaxf(smx[2],smx[3]));
    int n = 1 << *wbit;
    float nm1 = (float)(n-1);
    float rngc = fmaxf(__fsub_rn(fmx, fmn), 1e-8f);
    float sw = __fdiv_rn(nm1, rngc);
    float zp = __fmul_rn(sw, fmn);
    s_sw = sw; s_zp = zp;
    scale_w[row] = sw; zp_w[row] = zp;
    winv[row] = __fdiv_rn(rngc, nm1);
  }
  __syncthreads();
  float sw = s_sw, zp = s_zp;
  int qsum = 0; uint32_t lo = 0, hi = 0;
  for(int j=0;j<8;j++){
    int q = (int)rintf(__fsub_rn(__fmul_rn(sw, v[j]), zp));
    qsum += q;
    uint32_t u = (uint32_t)((q - 128) & 0xff);
    if(j<4) lo |= u << (8*j); else hi |= u << (8*(j-4));
  }
  uint32_t* qrow = (uint32_t*)(qw + (long long)row*din);
  qrow[tid*2] = lo; qrow[tid*2+1] = hi;
  int wsum = wave_sum(qsum);
  __shared__ int ssum[4];
  if(lane==0) ssum[wid] = wsum;
  __syncthreads();
  if(tid==0){
    int Sb = ssum[0]+ssum[1]+ssum[2]+ssum[3];
    cint[row] = 128*Sb - 128*128*din;   // bias term added in gemm epilogue
  }
}

// ============ 128x256 GEMM: A via 16KiB LDS dbuf (reg-staged), B direct-to-reg ============
// 4 waves (256 thr); wave w computes ALL 128 rows x cols w*64..+63.
// LDS traffic/tile/block: 8KB write + 32KB read (was 32+96 at 256x256/8w) ->
// LDS-port time ~55% of MFMA time instead of ~100%.
// Raw s_barrier + lgkmcnt(0) only: no vmcnt drain at barriers; compiler emits
// counted vmcnt for the reg-staged A and direct B loads automatically.
__global__ __launch_bounds__(256, 2) void k_gemm(
    const char* __restrict__ qx, const char* __restrict__ qw,
    const int* __restrict__ Sa, const int* __restrict__ cint,
    const float* __restrict__ scale_w, const float* __restrict__ winv,
    const float* __restrict__ zp_w, const float* __restrict__ bias,
    const int* __restrict__ wbit, const uint32_t* __restrict__ xmax_bits,
    float* __restrict__ out, int T, int dout, int din){
  __shared__ __align__(16) char Abuf[2][8192];
  const int tid = threadIdx.x, lane = tid & 63, wid = tid >> 6;
  const int tileN = blockIdx.x, tileM = blockIdx.y;
  const int nk = din / 64;

  // A staging: thread -> 16B chunk tid (row tid>>2, kchunk tid&3) and chunk tid+256
  const char* aSrc0 = qx + ((long long)tileM*128 + (tid>>2))*din + (tid&3)*16;
  const char* aSrc1 = aSrc0 + (long long)64*din;
  const int aLds = tid*16;

  // B direct: frag ni = rows wid*64+ni*16+(lane&15), kchunk lane>>4
  const char* bBase = qw + ((long long)tileN*256 + wid*64 + (lane&15))*din + (lane>>4)*16;
  const long long bNi = (long long)16*din;

  // LDS A-frag read: row (lane&15)+mi*16 at row*64, chunk (lane>>4)*16
  const int aRd = (lane&15)*64 + (lane>>4)*16;

  i32x4 acc[8][4] = {};
  i32x4 aR0, aR1, aN0, aN1, bR[4], bN[4];

  // prologue: stage A(0), preload A(1), B(0)
  aR0 = *(const i32x4*)(aSrc0);
  aR1 = *(const i32x4*)(aSrc1);
  *(i32x4*)(&Abuf[0][aLds])        = aR0;
  *(i32x4*)(&Abuf[0][aLds + 4096]) = aR1;
  aR0 = *(const i32x4*)(aSrc0 + 64);
  aR1 = *(const i32x4*)(aSrc1 + 64);
  #pragma unroll
  for(int ni=0; ni<4; ++ni) bR[ni] = *(const i32x4*)(bBase + ni*bNi);
  asm volatile("s_waitcnt lgkmcnt(0)" ::: "memory");
  __builtin_amdgcn_s_barrier();

  for(int t = 0; t < nk; ++t){
    const bool ldA = (t + 2 < nk), ldB = (t + 1 < nk);
    if(ldA){
      aN0 = *(const i32x4*)(aSrc0 + (long long)(t+2)*64);
      aN1 = *(const i32x4*)(aSrc1 + (long long)(t+2)*64);
    }
    if(ldB){
      #pragma unroll
      for(int ni=0; ni<4; ++ni) bN[ni] = *(const i32x4*)(bBase + ni*bNi + (long long)(t+1)*64);
    }
    const char* Ab = Abuf[t & 1];
    i32x4 af[8];
    #pragma unroll
    for(int mi=0; mi<8; ++mi) af[mi] = *(const i32x4*)(Ab + aRd + mi*1024);

    __builtin_amdgcn_s_setprio(1);
    #pragma unroll
    for(int mi=0; mi<8; ++mi)
      #pragma unroll
      for(int ni=0; ni<4; ++ni)
        acc[mi][ni] = __builtin_amdgcn_mfma_i32_16x16x64_i8(af[mi], bR[ni], acc[mi][ni], 0, 0, 0);
    __builtin_amdgcn_s_setprio(0);

    if(ldB){
      char* An = Abuf[(t+1) & 1];
      *(i32x4*)(An + aLds)        = aR0;   // compiler: counted vmcnt for aR0/aR1
      *(i32x4*)(An + aLds + 4096) = aR1;
      aR0 = aN0; aR1 = aN1;
      #pragma unroll
      for(int ni=0; ni<4; ++ni) bR[ni] = bN[ni];
    }
    asm volatile("s_waitcnt lgkmcnt(0)" ::: "memory");
    __builtin_amdgcn_s_barrier();
  }

  // epilogue: out = ((acc + 128*sa + cint + qb) + zp*sa) * (1/sx) * (1/sw)
  const int n = 1 << *wbit;
  const float nm1 = (float)(n-1);
  const float xmaxc = fmaxf(__uint_as_float(*xmax_bits), 1e-8f);
  const float sx = __fdiv_rn(nm1, xmaxc);
  const float inv_sx = __fdiv_rn(xmaxc, nm1);
  const int colL = tileN*256 + wid*64 + (lane & 15);
  const int rowL = tileM*128 + ((lane >> 4) * 4);
  float invc[4], zp4[4]; int ci4[4];
  #pragma unroll
  for(int ni=0; ni<4; ++ni){
    int o = colL + ni*16;
    float sw = scale_w[o];
    float qbf = rintf(__fmul_rn(__fmul_rn(bias[o], sw), sx));
    qbf = fminf(fmaxf(qbf, -(float)(n+1)), (float)n);
    ci4[ni] = cint[o] + (int)qbf;
    invc[ni] = __fmul_rn(winv[o], inv_sx);
    zp4[ni]  = zp_w[o];
  }
  #pragma unroll
  for(int mi=0; mi<8; ++mi){
    int rb = rowL + mi*16;
    int sav[4];
    #pragma unroll
    for(int r=0; r<4; ++r) sav[r] = Sa[rb + r];
    #pragma unroll
    for(int ni=0; ni<4; ++ni){
      #pragma unroll
      for(int r=0; r<4; ++r){
        int iv = acc[mi][ni][r] + 128*sav[r] + ci4[ni];
        float f = (float)iv + zp4[ni]*(float)sav[r];
        out[(long long)(rb + r)*dout + colL + ni*16] = __fmul_rn(f, invc[ni]);
      }
    }
  }
}

extern "C" void kernel_launch(void* const* d_in, const int* in_sizes, int n_in,
                              void* d_out, int out_size, void* d_ws, size_t ws_size,
                              hipStream_t stream){
  const float* x    = (const float*)d_in[0];
  const float* w    = (const float*)d_in[1];
  const float* bias = (const float*)d_in[2];
  const int*   wbit = (const int*)d_in[3];
  int dout = in_sizes[2];
  int din  = in_sizes[1] / dout;
  int T    = in_sizes[0] / din;

  char* ws = (char*)d_ws;
  uint32_t* xmax_bits = (uint32_t*)ws;          // +0
  uint32_t* cnt       = (uint32_t*)(ws + 64);   // spin counter
  size_t off = 256;
  int nQB = T / 8;                               // 1024 @ T=8192 -> 4 blocks/CU resident
  float* partials = (float*)(ws + off); off += 4*(size_t)nQB;
  float* scale_w = (float*)(ws + off); off += 4*(size_t)dout;
  float* zp_w    = (float*)(ws + off); off += 4*(size_t)dout;
  float* winv    = (float*)(ws + off); off += 4*(size_t)dout;
  int*   cint    = (int*)(ws + off);   off += 4*(size_t)dout;
  int*   Sa      = (int*)(ws + off);   off += 4*(size_t)T;
  off = (off + 255) & ~(size_t)255;
  char*  qw      = ws + off;           off += (size_t)dout*din;
  char*  qx      = ws + off;           off += (size_t)T*din;

  hipMemsetAsync(cnt, 0, 4, stream);
  k_fused_quant<<<nQB, 256, 0, stream>>>(x, wbit, partials, cnt, xmax_bits, qx, Sa, din, nQB);
  k_wstat<<<dout, 256, 0, stream>>>(w, wbit, scale_w, zp_w, winv, cint, qw, din);
  dim3 grid(dout/256, T/128);
  k_gemm<<<grid, 256, 0, stream>>>(qx, qw, Sa, cint, scale_w, winv, zp_w, bias, wbit, xmax_bits,
                                   (float*)d_out, T, dout, din);
}

// Round 7
// 80.343 us; speedup vs baseline: 2.7544x; 2.7544x over previous
//
#include <hip/hip_runtime.h>
#include <stdint.h>

typedef __attribute__((ext_vector_type(4))) int i32x4;

__device__ inline float wave_max(float v){ for(int o=32;o;o>>=1) v=fmaxf(v,__shfl_xor(v,o)); return v; }
__device__ inline float wave_min(float v){ for(int o=32;o;o>>=1) v=fminf(v,__shfl_xor(v,o)); return v; }
__device__ inline int   wave_sum(int v){ for(int o=32;o;o>>=1) v+=__shfl_xor(v,o); return v; }

__device__ inline void gload16(const void* g, void* l){
  __builtin_amdgcn_global_load_lds((const __attribute__((address_space(1))) char*)g,
                                   (__attribute__((address_space(3))) char*)l, 16, 0, 0);
}

// stage 1: per-block max -> partials[blockIdx.x]  (no atomics)
__global__ void k_xmax_partial(const float* __restrict__ x, long long n4,
                               float* __restrict__ partials){
  long long i = (long long)blockIdx.x*blockDim.x + threadIdx.x;
  long long stride = (long long)gridDim.x*blockDim.x;
  const float4* x4 = (const float4*)x;
  float m = 0.f;
  for(; i < n4; i += stride){
    float4 v = x4[i];
    m = fmaxf(m, fmaxf(fmaxf(v.x,v.y),fmaxf(v.z,v.w)));
  }
  m = wave_max(m);
  __shared__ float sm[4];
  int lane = threadIdx.x & 63, wid = threadIdx.x >> 6;
  if(lane==0) sm[wid] = m;
  __syncthreads();
  if(threadIdx.x==0)
    partials[blockIdx.x] = fmaxf(fmaxf(sm[0],sm[1]),fmaxf(sm[2],sm[3]));
}

// stage 2: one block reduces nPart partials
__global__ void k_xmax_final(const float* __restrict__ partials, int nPart,
                             uint32_t* __restrict__ xmax_bits){
  float m = 0.f;
  for(int i = threadIdx.x; i < nPart; i += 256) m = fmaxf(m, partials[i]);
  m = wave_max(m);
  __shared__ float sm[4];
  int lane = threadIdx.x & 63, wid = threadIdx.x >> 6;
  if(lane==0) sm[wid] = m;
  __syncthreads();
  if(threadIdx.x==0)
    *xmax_bits = __float_as_uint(fmaxf(fmaxf(sm[0],sm[1]),fmaxf(sm[2],sm[3])));
}

// one block (256 thr) per output channel row (bias folded in gemm epilogue)
__global__ void k_wstat(const float* __restrict__ w,
                        const int* __restrict__ wbit,
                        float* __restrict__ scale_w, float* __restrict__ zp_w,
                        float* __restrict__ winv,
                        int* __restrict__ cint, char* __restrict__ qw, int din){
  int row = blockIdx.x, tid = threadIdx.x;
  int lane = tid & 63, wid = tid >> 6;
  const float4* wr4 = (const float4*)(w + (long long)row*din);
  float4 a = wr4[tid*2], b = wr4[tid*2+1];
  float v[8] = {a.x,a.y,a.z,a.w,b.x,b.y,b.z,b.w};
  float mn = v[0], mx = v[0];
  for(int j=1;j<8;j++){ mn=fminf(mn,v[j]); mx=fmaxf(mx,v[j]); }
  float wmn = wave_min(mn), wmx = wave_max(mx);
  __shared__ float smn[4], smx[4];
  __shared__ float s_sw, s_zp;
  if(lane==0){ smn[wid]=wmn; smx[wid]=wmx; }
  __syncthreads();
  if(tid==0){
    float fmn = fminf(fminf(smn[0],smn[1]),fminf(smn[2],smn[3]));
    float fmx = fmaxf(fmaxf(smx[0],smx[1]),fmaxf(smx[2],smx[3]));
    int n = 1 << *wbit;
    float nm1 = (float)(n-1);
    float rngc = fmaxf(__fsub_rn(fmx, fmn), 1e-8f);
    float sw = __fdiv_rn(nm1, rngc);
    float zp = __fmul_rn(sw, fmn);
    s_sw = sw; s_zp = zp;
    scale_w[row] = sw; zp_w[row] = zp;
    winv[row] = __fdiv_rn(rngc, nm1);
  }
  __syncthreads();
  float sw = s_sw, zp = s_zp;
  int qsum = 0; uint32_t lo = 0, hi = 0;
  for(int j=0;j<8;j++){
    int q = (int)rintf(__fsub_rn(__fmul_rn(sw, v[j]), zp));   // exact replication, no fma
    qsum += q;
    uint32_t u = (uint32_t)((q - 128) & 0xff);
    if(j<4) lo |= u << (8*j); else hi |= u << (8*(j-4));
  }
  uint32_t* qrow = (uint32_t*)(qw + (long long)row*din);
  qrow[tid*2] = lo; qrow[tid*2+1] = hi;
  int wsum = wave_sum(qsum);
  __shared__ int ssum[4];
  if(lane==0) ssum[wid] = wsum;
  __syncthreads();
  if(tid==0){
    int Sb = ssum[0]+ssum[1]+ssum[2]+ssum[3];
    cint[row] = 128*Sb - 128*128*din;
  }
}

// one block (256 thr) per token row
__global__ void k_xquant(const float* __restrict__ x, const int* __restrict__ wbit,
                         const uint32_t* __restrict__ xmax_bits,
                         char* __restrict__ qx, int* __restrict__ Sa, int din){
  int row = blockIdx.x, tid = threadIdx.x;
  int lane = tid & 63, wid = tid >> 6;
  int n = 1 << *wbit;
  float nm1 = (float)(n-1);
  float sx = __fdiv_rn(nm1, fmaxf(__uint_as_float(*xmax_bits), 1e-8f));
  const float4* xr4 = (const float4*)(x + (long long)row*din);
  float4 a = xr4[tid*2], b = xr4[tid*2+1];
  float v[8] = {a.x,a.y,a.z,a.w,b.x,b.y,b.z,b.w};
  int qsum = 0; uint32_t lo = 0, hi = 0;
  for(int j=0;j<8;j++){
    int q = (int)rintf(__fmul_rn(sx, v[j]));
    qsum += q;
    uint32_t u = (uint32_t)((q - 128) & 0xff);
    if(j<4) lo |= u << (8*j); else hi |= u << (8*(j-4));
  }
  uint32_t* qrow = (uint32_t*)(qx + (long long)row*din);
  qrow[tid*2] = lo; qrow[tid*2+1] = hi;
  int wsum = wave_sum(qsum);
  __shared__ int ssum[4];
  if(lane==0) ssum[wid] = wsum;
  __syncthreads();
  if(tid==0) Sa[row] = ssum[0]+ssum[1]+ssum[2]+ssum[3];
}

// ======= 256x256 i8 GEMM, m201-style 4-phase/K-tile counted-vmcnt pipeline =======
// BK=128B, dbuf=2, LDS = 2 x (A 32K + B 32K) = 128 KiB. 8 waves (2M x 4N),
// per-wave 128x64. Half-tiles split ALONG K (ks0/ks1 = 16KB each): every wave
// consumes both halves => staging order == consumption order for all waves.
// Per K-tile: 4 phases {ds_read subtile; stage 1 half-tile (2 gload16); barrier;
// setprio; 16 MFMA; setprio; [vmcnt(4) at ph2,ph4]; barrier}. vmcnt(4) keeps the
// 2 newest half-tiles (4 loads) in flight - never drains to 0 in the main loop.
// Chunk swizzle (proven 0-conflict r3): src col ^= ((row>>1)&3), read chunk
// physo = ((lane>>4)^((lane>>1)&3))*16, linear LDS dest (rule #21).
__global__ __launch_bounds__(512, 2) void k_gemm(
    const char* __restrict__ qx, const char* __restrict__ qw,
    const int* __restrict__ Sa, const int* __restrict__ cint,
    const float* __restrict__ scale_w, const float* __restrict__ winv,
    const float* __restrict__ zp_w, const float* __restrict__ bias,
    const int* __restrict__ wbit, const uint32_t* __restrict__ xmax_bits,
    float* __restrict__ out, int T, int dout, int din){
  extern __shared__ char lds[];   // [buf:2][op:2(A,B)][ks:2][16384]
  const int tid = threadIdx.x, lane = tid & 63, wid = tid >> 6;
  const int wr = wid >> 2, wc = wid & 3;
  const int tileN = blockIdx.x, tileM = blockIdx.y;
  const int nt = din / 128;

  // staging: half-tile = 1024 chunks of 16B; thread handles chunks {tid, tid+512}
  const int i0 = tid, i1 = tid + 512;
  const int r0 = i0 >> 2, r1 = i1 >> 2;
  const int sc0 = ((i0 & 3) ^ ((r0 >> 1) & 3)) * 16;
  const int sc1 = ((i1 & 3) ^ ((r1 >> 1) & 3)) * 16;
  const char* aS0 = qx + ((long long)tileM*256 + r0)*din + sc0;
  const char* aS1 = qx + ((long long)tileM*256 + r1)*din + sc1;
  const char* bS0 = qw + ((long long)tileN*256 + r0)*din + sc0;
  const char* bS1 = qw + ((long long)tileN*256 + r1)*din + sc1;
  const int d0 = i0*16, d1 = i1*16;

  // ds_read addressing
  const int physo = (((lane >> 4) ^ ((lane >> 1) & 3)) * 16);
  const int arowL = wr*128 + (lane & 15);
  const int browL = wc*64  + (lane & 15);

  i32x4 acc[8][4] = {};
  i32x4 af[4], bf[4];

#define STAGE_A(KS, KOFF, NB) do{ \
    gload16(aS0 + (KOFF) + (KS)*64, (NB) + (KS)*16384 + d0); \
    gload16(aS1 + (KOFF) + (KS)*64, (NB) + (KS)*16384 + d1); }while(0)
#define STAGE_B(KS, KOFF, NB) do{ \
    gload16(bS0 + (KOFF) + (KS)*64, (NB) + 32768 + (KS)*16384 + d0); \
    gload16(bS1 + (KOFF) + (KS)*64, (NB) + 32768 + (KS)*16384 + d1); }while(0)

  // prologue: stage tile 0 in consumption order A0,B0,A1,B1; land ks0; barrier
  STAGE_A(0, 0, lds); STAGE_B(0, 0, lds);
  STAGE_A(1, 0, lds); STAGE_B(1, 0, lds);
  asm volatile("s_waitcnt vmcnt(4)" ::: "memory");
  __builtin_amdgcn_s_barrier();

  for(int t = 0; t < nt; ++t){
    char* Ab = lds + (t & 1)*65536;          // A base (current buf)
    char* Bb = Ab + 32768;                   // B base
    char* NB = lds + ((t & 1)^1)*65536;      // next buf
    const bool ld = (t + 1 < nt);
    const int koff = (t + 1)*128;

#define PH(MH, KS, DO_B, STAGE_STMT, VM_STMT) do{ \
    if(DO_B){ _Pragma("unroll") \
      for(int ni=0;ni<4;++ni) bf[ni] = *(const i32x4*)(Bb + (KS)*16384 + (browL + ni*16)*64 + physo); } \
    _Pragma("unroll") \
    for(int mi=0;mi<4;++mi) af[mi] = *(const i32x4*)(Ab + (KS)*16384 + (arowL + (MH)*64 + mi*16)*64 + physo); \
    STAGE_STMT; \
    __builtin_amdgcn_s_barrier(); \
    __builtin_amdgcn_s_setprio(1); \
    _Pragma("unroll") \
    for(int mi=0;mi<4;++mi){ _Pragma("unroll") \
      for(int ni=0;ni<4;++ni) \
        acc[(MH)*4+mi][ni] = __builtin_amdgcn_mfma_i32_16x16x64_i8(af[mi], bf[ni], acc[(MH)*4+mi][ni], 0,0,0); } \
    __builtin_amdgcn_s_setprio(0); \
    VM_STMT; \
    __builtin_amdgcn_s_barrier(); }while(0)

    PH(0, 0, true,  if(ld) STAGE_A(0, koff, NB), );
    PH(1, 0, false, if(ld) STAGE_B(0, koff, NB),
       if(ld){ asm volatile("s_waitcnt vmcnt(4)" ::: "memory"); }
       else  { asm volatile("s_waitcnt vmcnt(0)" ::: "memory"); });
    PH(0, 1, true,  if(ld) STAGE_A(1, koff, NB), );
    PH(1, 1, false, if(ld) STAGE_B(1, koff, NB),
       if(ld){ asm volatile("s_waitcnt vmcnt(4)" ::: "memory"); });
#undef PH
  }

  // epilogue: out = ((acc + 128*sa + cint + qb) + zp*sa) * (1/sx) * (1/sw)
  const int n = 1 << *wbit;
  const float nm1 = (float)(n-1);
  const float xmaxc = fmaxf(__uint_as_float(*xmax_bits), 1e-8f);
  const float sx = __fdiv_rn(nm1, xmaxc);
  const float inv_sx = __fdiv_rn(xmaxc, nm1);
  const int colL = tileN*256 + wc*64 + (lane & 15);
  const int rowL = tileM*256 + wr*128 + ((lane >> 4) * 4);
  float invc[4], zp4[4]; int ci4[4];
  #pragma unroll
  for(int ni=0; ni<4; ++ni){
    int o = colL + ni*16;
    float sw = scale_w[o];
    float qbf = rintf(__fmul_rn(__fmul_rn(bias[o], sw), sx));
    qbf = fminf(fmaxf(qbf, -(float)(n+1)), (float)n);
    ci4[ni] = cint[o] + (int)qbf;
    invc[ni] = __fmul_rn(winv[o], inv_sx);
    zp4[ni]  = zp_w[o];
  }
  #pragma unroll
  for(int mi=0; mi<8; ++mi){
    int rb = rowL + mi*16;
    int sav[4];
    #pragma unroll
    for(int r=0; r<4; ++r) sav[r] = Sa[rb + r];
    #pragma unroll
    for(int ni=0; ni<4; ++ni){
      #pragma unroll
      for(int r=0; r<4; ++r){
        int iv = acc[mi][ni][r] + 128*sav[r] + ci4[ni];
        float f = (float)iv + zp4[ni]*(float)sav[r];
        out[(long long)(rb + r)*dout + colL + ni*16] = __fmul_rn(f, invc[ni]);
      }
    }
  }
}

extern "C" void kernel_launch(void* const* d_in, const int* in_sizes, int n_in,
                              void* d_out, int out_size, void* d_ws, size_t ws_size,
                              hipStream_t stream){
  const float* x    = (const float*)d_in[0];
  const float* w    = (const float*)d_in[1];
  const float* bias = (const float*)d_in[2];
  const int*   wbit = (const int*)d_in[3];
  int dout = in_sizes[2];
  int din  = in_sizes[1] / dout;
  int T    = in_sizes[0] / din;

  const int NPART = 2048;
  char* ws = (char*)d_ws;
  uint32_t* xmax_bits = (uint32_t*)ws;
  size_t off = 256;
  float* partials = (float*)(ws + off); off += 4*(size_t)NPART;
  float* scale_w = (float*)(ws + off); off += 4*(size_t)dout;
  float* zp_w    = (float*)(ws + off); off += 4*(size_t)dout;
  float* winv    = (float*)(ws + off); off += 4*(size_t)dout;
  int*   cint    = (int*)(ws + off);   off += 4*(size_t)dout;
  int*   Sa      = (int*)(ws + off);   off += 4*(size_t)T;
  off = (off + 255) & ~(size_t)255;
  char*  qw      = ws + off;           off += (size_t)dout*din;
  char*  qx      = ws + off;           off += (size_t)T*din;

  long long n4 = (long long)T*din/4;
  k_xmax_partial<<<NPART, 256, 0, stream>>>(x, n4, partials);
  k_xmax_final<<<1, 256, 0, stream>>>(partials, NPART, xmax_bits);
  k_wstat<<<dout, 256, 0, stream>>>(w, wbit, scale_w, zp_w, winv, cint, qw, din);
  k_xquant<<<T, 256, 0, stream>>>(x, wbit, xmax_bits, qx, Sa, din);
  dim3 grid(dout/256, T/256);
  k_gemm<<<grid, 512, 131072, stream>>>(qx, qw, Sa, cint, scale_w, winv, zp_w, bias,
                                        wbit, xmax_bits, (float*)d_out, T, dout, din);
}